// Round 2
// 1258.938 us; speedup vs baseline: 1.5365x; 1.5365x over previous
//
#include <hip/hip_runtime.h>
#include <math.h>

#define BN_SC 0.9999950000375f
#define P2N   (6.283185307179586f / 126.f)
#define ATT_SCALE 0.35355339059327373f

typedef float v4f __attribute__((ext_vector_type(4)));
typedef short bf16x8 __attribute__((ext_vector_type(8)));
typedef float f32x4 __attribute__((ext_vector_type(4)));
typedef unsigned short u16;

enum { M_LOCAL = 0, M_GABOR = 1, M_BNRELU6 = 2, M_BIASRELU = 3 };

__device__ __forceinline__ u16 f2bf(float f) {
  unsigned u = __float_as_uint(f);
  return (u16)((u + 0x7FFFu + ((u >> 16) & 1u)) >> 16);
}
__device__ __forceinline__ float bf2f(u16 h) {
  return __uint_as_float(((unsigned)h) << 16);
}

// ------------- rpb bias pre-gather: rpbt[h][j*64+i] = rpb[relidx[i*64+j]*8+h] -------------
__global__ __launch_bounds__(256) void rpbprep_k(
    const float* __restrict__ rpb, const int* __restrict__ relidx, float* __restrict__ rpbt)
{
  int idx = blockIdx.x * 256 + threadIdx.x; // 32768
  int h = idx >> 12, r = idx & 4095, j = r >> 6, i = r & 63;
  rpbt[idx] = rpb[relidx[i * 64 + j] * 8 + h];
}

// ---------------- bias add (local branch: b_l1 + b_l2) ----------------
__global__ void bls_k(const float* __restrict__ a, const float* __restrict__ b,
                      float* __restrict__ o)
{ int i = threadIdx.x; o[i] = a[i] + b[i]; }

// -------- weight split: fp32 [nco][64][ntap] -> bf16 hi/lo [co_off+co][NT][64] --------
// Optional per-co scale (g * BN_SC) folded in.
__global__ __launch_bounds__(256)
void wsplit_k(const float* __restrict__ w, const float* __restrict__ gsc,
              u16* __restrict__ wh, u16* __restrict__ wl,
              int nco, int ntap, int co_off, int tap_off, int NT)
{
  int i = blockIdx.x * 256 + threadIdx.x;
  if (i >= nco * 64 * ntap) return;
  int t = i % ntap, q = i / ntap;
  int cin = q & 63, co = q >> 6;
  float v = w[i];
  if (gsc) v *= gsc[co_off + co] * BN_SC;
  u16 h = f2bf(v);
  u16 l = f2bf(v - bf2f(h));
  int dst = ((co_off + co) * NT + tap_off + t) * 64 + cin;
  wh[dst] = h; wl[dst] = l;
}

// -------- input split+transpose: fp32 NCHW [8][64][HW][HW] -> bf16 hi/lo NHWC --------
template<int HW>
__global__ __launch_bounds__(256)
void xsplit_k(const float* __restrict__ in, u16* __restrict__ xh, u16* __restrict__ xl)
{
  __shared__ float t[64 * (HW + 1)];
  const int by = blockIdx.x;          // b*HW + y
  const int tid = threadIdx.x;
  const int b = by / HW, y = by - b * HW;
  const float* ip = in + (size_t)b * 64 * HW * HW + (size_t)y * HW;
  for (int e = tid; e < 64 * HW; e += 256) {
    int cin = e / HW, x = e - cin * HW;
    t[cin * (HW + 1) + x] = ip[(size_t)cin * HW * HW + x];
  }
  __syncthreads();
  u16* oh = xh + (size_t)by * HW * 64;
  u16* ol = xl + (size_t)by * HW * 64;
  for (int e = tid; e < 64 * HW; e += 256) {
    int x = e >> 6, cin = e & 63;
    float v = t[cin * (HW + 1) + x];
    u16 h = f2bf(v);
    oh[e] = h;
    ol[e] = f2bf(v - bf2f(h));
  }
}

// ================= MFMA conv3x3 (split-bf16, 3-MFMA fp32-accurate) =================
// Block: 16x16 output pixels x 64 co. 4 waves = 2(co half) x 2(8-row half).
// LDS: 18x18 halo, per pixel-row 144 B = [hi 4x16B][lo 4x16B][16B pad].
// A (weights) read from global (L2-hot), layout [co][NT][64cin] bf16, prefetched per tap.
// NT=10 for LOCAL (tap 9 = fused 1x1 at center), else 9.
template<int MODE, int NT, int IN_HW, int OUT_HW, int PAD>
__global__ __launch_bounds__(256, 3)
void convmf_k(const u16* __restrict__ xh, const u16* __restrict__ xl,
              const u16* __restrict__ wh, const u16* __restrict__ wl,
              const float* __restrict__ ba, const float* __restrict__ bb,
              float* __restrict__ out)
{
  __shared__ uint4 lds4[2916];               // 324 * 144 B = 46656
  char* lds = (char*)lds4;
  const int tid = threadIdx.x;
  const int lane = tid & 63;
  const int wv = __builtin_amdgcn_readfirstlane(tid >> 6);
  const int wco = wv & 1, wpx = wv >> 1;
  const int b = blockIdx.y;
  const int oy0 = (blockIdx.x >> 3) * 16, ox0 = (blockIdx.x & 7) * 16;
  const int iy0 = oy0 - PAD, ix0 = ox0 - PAD;
  const int l15 = lane & 15, l4 = lane >> 4;
  const int bboff = l15 * 144 + l4 * 16;
  const int aoff  = l15 * (NT * 64) + l4 * 8;
  const u16* wh0 = wh + wco * 32 * NT * 64 + aoff;
  const u16* wl0 = wl + wco * 32 * NT * 64 + aoff;

  f32x4 acc[2][8];
#pragma unroll
  for (int f = 0; f < 2; ++f)
#pragma unroll
    for (int r = 0; r < 8; ++r) { f32x4 z = {0.f, 0.f, 0.f, 0.f}; acc[f][r] = z; }

#pragma unroll 1
  for (int cc = 0; cc < 64; cc += 32) {
    __syncthreads();
    // stage 18x18 halo, cin chunk [cc, cc+32): hi and lo, 16B per (pixel, part)
    for (int e = tid; e < 2592; e += 256) {
      int pix = e >> 3, part = e & 7;
      int lr = pix / 18, lc = pix - lr * 18;
      int iy = iy0 + lr, ix = ix0 + lc;
      uint4 v = make_uint4(0u, 0u, 0u, 0u);
      if ((unsigned)iy < (unsigned)IN_HW && (unsigned)ix < (unsigned)IN_HW) {
        const u16* s = ((part < 4) ? xh : xl)
            + ((size_t)(b * IN_HW + iy) * IN_HW + ix) * 64 + cc + (part & 3) * 8;
        v = *(const uint4*)s;
      }
      *(uint4*)(lds + pix * 144 + part * 16) = v;
    }
    __syncthreads();

    // A frags for tap 0
    bf16x8 ah0 = *(const bf16x8*)(wh0 + cc);
    bf16x8 al0 = *(const bf16x8*)(wl0 + cc);
    bf16x8 ah1 = *(const bf16x8*)(wh0 + 16 * NT * 64 + cc);
    bf16x8 al1 = *(const bf16x8*)(wl0 + 16 * NT * 64 + cc);

#pragma unroll 1
    for (int t = 0; t < NT; ++t) {
      // prefetch next tap's A frags (L2-hot global)
      int tn = (t + 1 < NT) ? t + 1 : t;
      bf16x8 nh0 = *(const bf16x8*)(wh0 + tn * 64 + cc);
      bf16x8 nl0 = *(const bf16x8*)(wl0 + tn * 64 + cc);
      bf16x8 nh1 = *(const bf16x8*)(wh0 + 16 * NT * 64 + tn * 64 + cc);
      bf16x8 nl1 = *(const bf16x8*)(wl0 + 16 * NT * 64 + tn * 64 + cc);
      int te = (t >= 9) ? 4 : t;            // tap 9 (1x1) = center (1,1)
      int dy = te / 3;
      int dx = te - dy * 3;
      const char* pb = lds + ((wpx * 8 + dy) * 18 + dx) * 144 + bboff;
#pragma unroll
      for (int r = 0; r < 8; ++r) {
        bf16x8 bh = *(const bf16x8*)(pb + r * 2592);
        bf16x8 bl = *(const bf16x8*)(pb + r * 2592 + 64);
        acc[0][r] = __builtin_amdgcn_mfma_f32_16x16x32_bf16(ah0, bh, acc[0][r], 0, 0, 0);
        acc[1][r] = __builtin_amdgcn_mfma_f32_16x16x32_bf16(ah1, bh, acc[1][r], 0, 0, 0);
        acc[0][r] = __builtin_amdgcn_mfma_f32_16x16x32_bf16(ah0, bl, acc[0][r], 0, 0, 0);
        acc[0][r] = __builtin_amdgcn_mfma_f32_16x16x32_bf16(al0, bh, acc[0][r], 0, 0, 0);
        acc[1][r] = __builtin_amdgcn_mfma_f32_16x16x32_bf16(ah1, bl, acc[1][r], 0, 0, 0);
        acc[1][r] = __builtin_amdgcn_mfma_f32_16x16x32_bf16(al1, bh, acc[1][r], 0, 0, 0);
      }
      ah0 = nh0; al0 = nl0; ah1 = nh1; al1 = nl1;
    }
  }

  // ---- epilogue: C/D frag (col = lane&15 -> pixel x, row = (lane>>4)*4+j -> co) ----
  const int ox = ox0 + l15;
#pragma unroll
  for (int f = 0; f < 2; ++f) {
    const int cb = wco * 32 + f * 16 + l4 * 4;
    float bias[4];
#pragma unroll
    for (int j = 0; j < 4; ++j) {
      int c = cb + j;
      bias[j] = (MODE == M_GABOR && c >= 32) ? bb[c - 32] : ba[c];
    }
#pragma unroll
    for (int r = 0; r < 8; ++r) {
      int oy = oy0 + wpx * 8 + r;
      if (OUT_HW != 128 && (oy >= OUT_HW || ox >= OUT_HW)) continue;
#pragma unroll
      for (int j = 0; j < 4; ++j) {
        float v = acc[f][r][j] + bias[j];
        if (MODE == M_BNRELU6) v = fminf(fmaxf(v, 0.f), 6.f);
        if (MODE == M_BIASRELU) v = fmaxf(v, 0.f);
        out[(((size_t)(b * 64) + cb + j) * OUT_HW + oy) * OUT_HW + ox] = v;
      }
    }
  }
}

// -------- fp32 register-tiled stride-2 conv3x3 valid (125 -> 62), + bias + relu --------
__global__ __launch_bounds__(256)
void convgc_t(const float* __restrict__ in, const float* __restrict__ w,
              const float* __restrict__ bias, float* __restrict__ out)
{
  __shared__ float tile[4 * 33 * 35];
  __shared__ float wt[4 * 9 * 32];
  const int tid = threadIdx.x;
  const int tx = tid & 7, ty = (tid >> 3) & 7, tc = tid >> 6;
  const int bx = blockIdx.x & 3, by = blockIdx.x >> 2;
  const int b = blockIdx.y, zg = blockIdx.z;
  const int x0 = bx * 16, y0 = by * 16;
  const float* inb = in + (size_t)b * 64 * 125 * 125;

  float acc[8][2][2];
#pragma unroll
  for (int a = 0; a < 8; ++a)
#pragma unroll
    for (int py = 0; py < 2; ++py)
#pragma unroll
      for (int px = 0; px < 2; ++px) acc[a][py][px] = 0.f;

  for (int cc = 0; cc < 64; cc += 4) {
    __syncthreads();
    for (int e = tid; e < 4 * 33 * 33; e += 256) {
      int ci = e / 1089, r = e - ci * 1089;
      int row = r / 33, col = r - row * 33;
      int iy = 2 * y0 + row, ix = 2 * x0 + col;
      float v = 0.f;
      if (iy < 125 && ix < 125)
        v = inb[((size_t)(cc + ci) * 125 + iy) * 125 + ix];
      tile[ci * 1155 + row * 35 + col] = v;
    }
    for (int e = tid; e < 1152; e += 256) {
      int co = e & 31, q = e >> 5;
      int ci = q / 9, o = q - ci * 9;
      wt[q * 32 + co] = w[((size_t)(zg * 32 + co) * 64 + cc + ci) * 9 + o];
    }
    __syncthreads();
#pragma unroll
    for (int ci = 0; ci < 4; ++ci) {
      float p[5][5];
#pragma unroll
      for (int r = 0; r < 5; ++r)
#pragma unroll
        for (int c2 = 0; c2 < 5; ++c2)
          p[r][c2] = tile[ci * 1155 + (4 * ty + r) * 35 + 4 * tx + c2];
#pragma unroll
      for (int o = 0; o < 9; ++o) {
        const int dy = o / 3, dx = o - dy * 3;
        v4f w0 = *(const v4f*)&wt[(ci * 9 + o) * 32 + tc * 8];
        v4f w1 = *(const v4f*)&wt[(ci * 9 + o) * 32 + tc * 8 + 4];
#pragma unroll
        for (int py = 0; py < 2; ++py)
#pragma unroll
          for (int px = 0; px < 2; ++px) {
            float pv = p[2 * py + dy][2 * px + dx];
#pragma unroll
            for (int a = 0; a < 4; ++a) {
              acc[a][py][px]     += pv * w0[a];
              acc[a + 4][py][px] += pv * w1[a];
            }
          }
      }
    }
  }

#pragma unroll
  for (int a = 0; a < 8; ++a) {
    const int c = zg * 32 + tc * 8 + a;
    const float bv = bias[c];
#pragma unroll
    for (int py = 0; py < 2; ++py) {
      int oy = y0 + ty * 2 + py;
      if (oy >= 62) continue;
      float* op = out + (((size_t)b * 64 + c) * 62 + oy) * 62;
#pragma unroll
      for (int px = 0; px < 2; ++px) {
        int ox = x0 + tx * 2 + px;
        if (ox >= 62) continue;
        op[ox] = fmaxf(acc[a][py][px] + bv, 0.f);
      }
    }
  }
}

// ======================= DFT (126-pt), table-based, Hermitian-half =======================

__global__ __launch_bounds__(64)
void dft_rows_fwd_k(const float* __restrict__ in, float* __restrict__ outC, int planeBase)
{
  __shared__ float2 r2[63];
  __shared__ float2 T[126];
  const int lp = blockIdx.x / 126, n1 = blockIdx.x % 126;
  const int tid = threadIdx.x;
  const float2* row = (const float2*)(in + (size_t)(planeBase + lp) * 15876 + (size_t)n1 * 126);
  if (tid < 63) r2[tid] = row[tid];
  for (int e = tid; e < 126; e += 64) { float s, c; sincosf(P2N * (float)e, &s, &c); T[e] = make_float2(c, s); }
  __syncthreads();
  const int k2 = tid;
  const int inc = (2 * k2) % 126;
  int m = 0;
  float Er = 0.f, Ei = 0.f, Or = 0.f, Oi = 0.f;
  for (int n = 0; n < 63; ++n) {
    float2 rv = r2[n];
    float2 t = T[m];
    Er += rv.x * t.x; Ei -= rv.x * t.y;
    Or += rv.y * t.x; Oi -= rv.y * t.y;
    m += inc; if (m >= 126) m -= 126;
  }
  float c = T[k2].x, s = T[k2].y;
  float2* o = (float2*)(outC + (size_t)lp * 16128 + (size_t)n1 * 128);
  o[k2] = make_float2(Er + c * Or + s * Oi, Ei + c * Oi - s * Or);
}

__global__ __launch_bounds__(256)
void dft_cols_fwd_mask_k(const float* __restrict__ inC, float* __restrict__ outC)
{
  __shared__ float2 S[4032];
  __shared__ float2 T[126];
  const int lp = blockIdx.x >> 1, gbase = (blockIdx.x & 1) * 32;
  const int tid = threadIdx.x;
  if (tid < 126) { float s, c; sincosf(P2N * (float)tid, &s, &c); T[tid] = make_float2(c, s); }
  const float2* src = (const float2*)(inC + (size_t)lp * 16128);
  for (int e = tid; e < 4032; e += 256) {
    int n1 = e >> 5, c = e & 31;
    S[e] = src[n1 * 64 + gbase + c];
  }
  __syncthreads();
  float2* dst = (float2*)(outC + (size_t)lp * 16128);
  for (int e = tid; e < 2016; e += 256) {
    int k1 = e >> 5, c = e & 31;
    int k2 = gbase + c;
    int inc = 2 * k1;
    int me = 0, mo = k1;
    float Er = 0.f, Ei = 0.f, Or = 0.f, Oi = 0.f;
    for (int u = 0; u < 63; ++u) {
      float2 s0 = S[(2 * u) * 32 + c];
      float2 t0 = T[me];
      Er += s0.x * t0.x + s0.y * t0.y;
      Ei += s0.y * t0.x - s0.x * t0.y;
      float2 s1 = S[(2 * u + 1) * 32 + c];
      float2 t1 = T[mo];
      Or += s1.x * t1.x + s1.y * t1.y;
      Oi += s1.y * t1.x - s1.x * t1.y;
      me += inc; if (me >= 126) me -= 126;
      mo += inc; if (mo >= 126) mo -= 126;
    }
    int f2 = (k2 <= 62) ? k2 : k2 - 126;
    float ar = Er + Or, ai = Ei + Oi;
    float br = Er - Or, bi = Ei - Oi;
    float sa = (k1 * k1 + f2 * f2 > 1600) ? sqrtf(ar * ar + ai * ai) * (1.f / 15876.f) : 0.f;
    int f1b = k1 - 63;
    float sb = (f1b * f1b + f2 * f2 > 1600) ? sqrtf(br * br + bi * bi) * (1.f / 15876.f) : 0.f;
    dst[(size_t)k1 * 64 + k2]        = make_float2(ar * sa, ai * sa);
    dst[(size_t)(k1 + 63) * 64 + k2] = make_float2(br * sb, bi * sb);
  }
}

__global__ __launch_bounds__(256)
void dft_cols_inv_k(const float* __restrict__ inC, float* __restrict__ outC)
{
  __shared__ float2 S[4032];
  __shared__ float2 T[126];
  const int lp = blockIdx.x >> 1, gbase = (blockIdx.x & 1) * 32;
  const int tid = threadIdx.x;
  if (tid < 126) { float s, c; sincosf(P2N * (float)tid, &s, &c); T[tid] = make_float2(c, s); }
  const float2* src = (const float2*)(inC + (size_t)lp * 16128);
  for (int e = tid; e < 4032; e += 256) {
    int k1 = e >> 5, c = e & 31;
    S[e] = src[k1 * 64 + gbase + c];
  }
  __syncthreads();
  float2* dst = (float2*)(outC + (size_t)lp * 16128);
  for (int e = tid; e < 2016; e += 256) {
    int n1 = e >> 5, c = e & 31;
    int k2 = gbase + c;
    int inc = (2 * n1) % 126;
    int me = 0, mo = n1;
    float Er = 0.f, Ei = 0.f, Or = 0.f, Oi = 0.f;
    for (int u = 0; u < 63; ++u) {
      float2 s0 = S[(2 * u) * 32 + c];
      float2 t0 = T[me];
      Er += s0.x * t0.x - s0.y * t0.y;
      Ei += s0.x * t0.y + s0.y * t0.x;
      float2 s1 = S[(2 * u + 1) * 32 + c];
      float2 t1 = T[mo];
      Or += s1.x * t1.x - s1.y * t1.y;
      Oi += s1.x * t1.y + s1.y * t1.x;
      me += inc; if (me >= 126) me -= 126;
      mo += inc; if (mo >= 126) mo -= 126;
    }
    dst[(size_t)n1 * 64 + k2]        = make_float2(Er + Or, Ei + Oi);
    dst[(size_t)(n1 + 63) * 64 + k2] = make_float2(Er - Or, Ei - Oi);
  }
}

__global__ __launch_bounds__(128)
void dft_rows_inv_mix_k(const float* __restrict__ inC, const float* __restrict__ xc0,
                        const float* __restrict__ gb_w, float* __restrict__ out, int planeBase)
{
  __shared__ float2 Z[64];
  __shared__ float2 T[126];
  const int lp = blockIdx.x / 126, n1 = blockIdx.x % 126;
  const int tid = threadIdx.x;
  const float2* src = (const float2*)(inC + (size_t)lp * 16128 + (size_t)n1 * 128);
  if (tid < 64) Z[tid] = src[tid];
  if (tid < 126) { float s, c; sincosf(P2N * (float)tid, &s, &c); T[tid] = make_float2(c, s); }
  __syncthreads();
  const int n2 = tid;
  if (n2 < 126) {
    float a = Z[0].x + ((n2 & 1) ? -Z[63].x : Z[63].x);
    float acc = 0.f;
    int m = n2;
    for (int k2 = 1; k2 < 63; ++k2) {
      float2 z = Z[k2];
      float2 t = T[m];
      acc += z.x * t.x - z.y * t.y;
      m += n2; if (m >= 126) m -= 126;
    }
    a += 2.f * acc;
    float w0 = fmaxf(gb_w[0], 0.f), w1 = fmaxf(gb_w[1], 0.f);
    float inv = 1.f / (w0 + w1 + 1e-8f);
    size_t gi = (size_t)(planeBase + lp) * 15876 + (size_t)n1 * 126 + n2;
    out[gi] = (w0 * inv) * fabsf(a) + (w1 * inv) * xc0[gi];
  }
}

// ---------------- maxpool 2x2 stride1: 126 -> 125 ----------------
__global__ __launch_bounds__(256) void mp1_k(const float* __restrict__ in, float* __restrict__ out)
{
  int idx = blockIdx.x * 256 + threadIdx.x;
  if (idx >= 512 * 125 * 125) return;
  int x = idx % 125, y = (idx / 125) % 125, p = idx / 15625;
  const float* ip = in + (size_t)p * 15876 + (size_t)y * 126 + x;
  out[idx] = fmaxf(fmaxf(ip[0], ip[1]), fmaxf(ip[126], ip[127]));
}

// ---------------- maxpool 2x2 stride2: 62 -> 31 ----------------
__global__ __launch_bounds__(256) void mp2_k(const float* __restrict__ in, float* __restrict__ out)
{
  int idx = blockIdx.x * 256 + threadIdx.x;
  if (idx >= 512 * 31 * 31) return;
  int x = idx % 31, y = (idx / 31) % 31, p = idx / 961;
  const float* ip = in + (size_t)p * 3844 + (size_t)(2 * y) * 62 + 2 * x;
  out[idx] = fmaxf(fmaxf(ip[0], ip[1]), fmaxf(ip[62], ip[63]));
}

// ---------------- bilinear resize 31 -> 128 ----------------
__global__ __launch_bounds__(256) void resize_k(const float* __restrict__ in, float* __restrict__ out)
{
  int idx = blockIdx.x * 256 + threadIdx.x;
  if (idx >= 512 * 128 * 128) return;
  int x = idx & 127, y = (idx >> 7) & 127, p = idx >> 14;
  float sy = (y + 0.5f) * (31.f / 128.f) - 0.5f; sy = fminf(fmaxf(sy, 0.f), 30.f);
  float sx = (x + 0.5f) * (31.f / 128.f) - 0.5f; sx = fminf(fmaxf(sx, 0.f), 30.f);
  int y0 = (int)sy; float fy = sy - (float)y0; int y1 = min(y0 + 1, 30);
  int x0 = (int)sx; float fx = sx - (float)x0; int x1 = min(x0 + 1, 30);
  const float* ip = in + (size_t)p * 961;
  float v = (1.f - fy) * ((1.f - fx) * ip[y0 * 31 + x0] + fx * ip[y0 * 31 + x1])
          + fy         * ((1.f - fx) * ip[y1 * 31 + x0] + fx * ip[y1 * 31 + x1]);
  out[idx] = v;
}

// ---------------- 1x1 conv (w_gc2 + bias) + log_softmax over 64 channels ----------------
__global__ __launch_bounds__(256)
void pwlsm_k(const float* __restrict__ in, const float* __restrict__ w,
             const float* __restrict__ bias, float* __restrict__ out)
{
  __shared__ float zs[64 * 256];
  int idx = blockIdx.x * 256 + threadIdx.x;
  int b = idx >> 14, px = idx & 16383;
  const float* ip = in + ((size_t)b << 20) + px;
  float v[64];
#pragma unroll
  for (int i = 0; i < 64; ++i) v[i] = ip[(size_t)i << 14];
  float m = -1e30f;
  for (int co = 0; co < 64; ++co) {
    float s = bias[co];
    const float* wk = w + co * 64;
#pragma unroll
    for (int i = 0; i < 64; ++i) s += v[i] * wk[i];
    zs[co * 256 + threadIdx.x] = s;
    m = fmaxf(m, s);
  }
  float sum = 0.f;
  for (int co = 0; co < 64; ++co) sum += __expf(zs[co * 256 + threadIdx.x] - m);
  float lse = m + __logf(sum);
  float* op = out + ((size_t)b << 20) + px;
  for (int co = 0; co < 64; ++co) op[(size_t)co << 14] = zs[co * 256 + threadIdx.x] - lse;
}

// ---------------- windowed attention: wave-per-head, register softmax ----------------
__global__ __launch_bounds__(256)
void attn_w_k(const float* __restrict__ x, const float* __restrict__ wqkv,
              const float* __restrict__ rpbt, float* __restrict__ o_out)
{
  __shared__ float xt[4096];            // [cin][pix] 16 KB
  __shared__ float kvb[4][2][64][8];    // [wave][k|v][j][d] 16 KB
  const int tid = threadIdx.x;
  const int lane = tid & 63;
  const int wv = __builtin_amdgcn_readfirstlane(tid >> 6);
  const int b = blockIdx.x >> 8, gy = (blockIdx.x >> 4) & 15, gx = blockIdx.x & 15;
  const int y0 = gy * 8, x0 = gx * 8;

  for (int e = tid; e < 4096; e += 256) {
    int cin = e >> 6, pix = e & 63;
    xt[e] = x[((size_t)(b * 64 + cin) * 128 + (y0 + (pix >> 3))) * 128 + x0 + (pix & 7)];
  }
  __syncthreads();

  const int row = y0 + (lane >> 3), col = x0 + (lane & 7);

  for (int hh = 0; hh < 2; ++hh) {
    const int h = hh * 4 + wv;      // wave-uniform
    const float* wq = wqkv + (size_t)(h * 8) * 64;
    const float* wk = wqkv + (size_t)(64 + h * 8) * 64;
    const float* wvv = wqkv + (size_t)(128 + h * 8) * 64;
    float q[8], kk[8], vv[8];
#pragma unroll
    for (int d = 0; d < 8; ++d) { q[d] = 0.f; kk[d] = 0.f; vv[d] = 0.f; }
    for (int cb = 0; cb < 64; cb += 4) {
      float xv0 = xt[(cb + 0) * 64 + lane];
      float xv1 = xt[(cb + 1) * 64 + lane];
      float xv2 = xt[(cb + 2) * 64 + lane];
      float xv3 = xt[(cb + 3) * 64 + lane];
#pragma unroll
      for (int d = 0; d < 8; ++d) {
        float4 a = *(const float4*)(wq + d * 64 + cb);
        q[d] += xv0 * a.x + xv1 * a.y + xv2 * a.z + xv3 * a.w;
        float4 bq = *(const float4*)(wk + d * 64 + cb);
        kk[d] += xv0 * bq.x + xv1 * bq.y + xv2 * bq.z + xv3 * bq.w;
        float4 cq = *(const float4*)(wvv + d * 64 + cb);
        vv[d] += xv0 * cq.x + xv1 * cq.y + xv2 * cq.z + xv3 * cq.w;
      }
    }
#pragma unroll
    for (int d = 0; d < 8; ++d) {
      kvb[wv][0][lane][d] = kk[d];
      kvb[wv][1][lane][d] = vv[d];
    }
    __syncthreads();

    const float* rb = rpbt + h * 4096;
    float P[64];
    float m = -1e30f;
#pragma unroll
    for (int j = 0; j < 64; ++j) {
      float4 k0 = *(const float4*)&kvb[wv][0][j][0];
      float4 k1 = *(const float4*)&kvb[wv][0][j][4];
      float s = q[0] * k0.x + q[1] * k0.y + q[2] * k0.z + q[3] * k0.w
              + q[4] * k1.x + q[5] * k1.y + q[6] * k1.z + q[7] * k1.w;
      s = s * ATT_SCALE + rb[j * 64 + lane];
      P[j] = s;
      m = fmaxf(m, s);
    }
    float sum = 0.f;
#pragma unroll
    for (int j = 0; j < 64; ++j) { float p = __expf(P[j] - m); P[j] = p; sum += p; }
    float inv = 1.f / sum;

    float acc[8];
#pragma unroll
    for (int d = 0; d < 8; ++d) acc[d] = 0.f;
#pragma unroll
    for (int j = 0; j < 64; ++j) {
      float p = P[j];
      float4 v0 = *(const float4*)&kvb[wv][1][j][0];
      float4 v1 = *(const float4*)&kvb[wv][1][j][4];
      acc[0] += p * v0.x; acc[1] += p * v0.y; acc[2] += p * v0.z; acc[3] += p * v0.w;
      acc[4] += p * v1.x; acc[5] += p * v1.y; acc[6] += p * v1.z; acc[7] += p * v1.w;
    }
#pragma unroll
    for (int d = 0; d < 8; ++d)
      o_out[((size_t)(b * 64 + h * 8 + d) * 128 + row) * 128 + col] = acc[d] * inv;
    __syncthreads();
  }
}

// ------- directional avg pools (reflect+zero pad semantics) + add local -------
__global__ __launch_bounds__(256)
void avgadd_k(const float* __restrict__ o, const float* __restrict__ loc, float* __restrict__ out)
{
  int idx = blockIdx.x * 256 + threadIdx.x;
  if (idx >= 8388608) return;
  int x = idx & 127, y = (idx >> 7) & 127;
  size_t p = (size_t)(idx >> 14);
  const float* op = o + (p << 14);
  float s1 = 0.f, s2 = 0.f;
#pragma unroll
  for (int t = 0; t < 8; ++t) {
    int r = y - 3 + t;
    if (r >= 0 && r <= 128) { int rr = (r == 128) ? 126 : r; s1 += op[rr * 128 + x]; }
    int cc = x - 3 + t;
    if (cc >= 0 && cc <= 128) { int ss = (cc == 128) ? 126 : cc; s2 += op[y * 128 + ss]; }
  }
  out[idx] = 0.125f * (s1 + s2) + loc[idx];
}

// ---------------- depthwise 8x8 conv (pad_out + pad3, zero) + BN ----------------
__global__ __launch_bounds__(256)
void dw_k(const float* __restrict__ in, const float* __restrict__ w,
          const float* __restrict__ g, const float* __restrict__ bb, float* __restrict__ out)
{
  __shared__ float t[23 * 23];
  const int tid = threadIdx.x;
  const int tx = tid & 15, ty = tid >> 4;
  const int x0 = blockIdx.x * 16, y0 = blockIdx.y * 16;
  const int pc = blockIdx.z;
  const int c = pc & 63;
  const float* ip = in + (size_t)pc * 16384;
  for (int e = tid; e < 529; e += 256) {
    int yy = e / 23, xx = e % 23;
    int iy = y0 + yy - 3, ix = x0 + xx - 3;
    t[e] = (iy >= 0 && iy < 128 && ix >= 0 && ix < 128) ? ip[iy * 128 + ix] : 0.f;
  }
  __syncthreads();
  const float* wk = w + c * 64;
  float s = 0.f;
#pragma unroll
  for (int ky = 0; ky < 8; ++ky)
#pragma unroll
    for (int kx = 0; kx < 8; ++kx)
      s += t[(ty + ky) * 23 + tx + kx] * wk[ky * 8 + kx];
  out[(size_t)pc * 16384 + (y0 + ty) * 128 + x0 + tx] = s * (g[c] * BN_SC) + bb[c];
}

// ---------------- final 1x1 conv (w_pw, no bias) ----------------
__global__ __launch_bounds__(256)
void pw_k(const float* __restrict__ in, const float* __restrict__ w, float* __restrict__ out)
{
  int idx = blockIdx.x * 256 + threadIdx.x;
  int b = idx >> 14, px = idx & 16383;
  const float* ip = in + ((size_t)b << 20) + px;
  float v[64];
#pragma unroll
  for (int i = 0; i < 64; ++i) v[i] = ip[(size_t)i << 14];
  float* op = out + ((size_t)b << 20) + px;
  for (int co = 0; co < 64; ++co) {
    const float* wk = w + co * 64;
    float s = 0.f;
#pragma unroll
    for (int i = 0; i < 64; ++i) s += v[i] * wk[i];
    op[(size_t)co << 14] = s;
  }
}

// =======================================================================
extern "C" void kernel_launch(void* const* d_in, const int* in_sizes, int n_in,
                              void* d_out, int out_size, void* d_ws, size_t ws_size,
                              hipStream_t stream)
{
  const float* x      = (const float*)d_in[0];
  const float* w_qkv  = (const float*)d_in[1];
  const float* w_l1   = (const float*)d_in[2];
  const float* g_l1   = (const float*)d_in[3];
  const float* b_l1   = (const float*)d_in[4];
  const float* w_l2   = (const float*)d_in[5];
  const float* g_l2   = (const float*)d_in[6];
  const float* b_l2   = (const float*)d_in[7];
  const float* f_cos  = (const float*)d_in[8];
  const float* f_sin  = (const float*)d_in[9];
  const float* gb_b1  = (const float*)d_in[10];
  const float* gb_b2  = (const float*)d_in[11];
  const float* gb_w   = (const float*)d_in[12];
  const float* w_post = (const float*)d_in[13];
  const float* g_post = (const float*)d_in[14];
  const float* b_post = (const float*)d_in[15];
  const float* w_gc   = (const float*)d_in[16];
  const float* b_gc   = (const float*)d_in[17];
  const float* w_gc1  = (const float*)d_in[18];
  const float* b_gc1  = (const float*)d_in[19];
  const float* w_gc2  = (const float*)d_in[20];
  const float* b_gc2  = (const float*)d_in[21];
  const float* rpb    = (const float*)d_in[22];
  const float* w_dw   = (const float*)d_in[23];
  const float* g_proj = (const float*)d_in[24];
  const float* b_proj = (const float*)d_in[25];
  const float* w_pw   = (const float*)d_in[26];
  const int*   relidx = (const int*)d_in[27];
  float* out = (float*)d_out;

  // Workspace map (stays inside the round-2-proven 102,238,208-byte footprint):
  //  R1   [0,        33554432)   fp32 scratch A
  //  R2   [33554432, 67108864)   fp32 scratch B; also XH_A/XL_A for LOCAL conv
  //  R3/C1[67108864, 83623936)   FFT C1 / convgc out / out0; also XH_B
  //  C2   [83623936, 100139008)  FFT C2; XL_B starts at 83886080
  //  XC5  [100139008,102107136)  steps mp2->resize only
  //  W    [100663296,100827392)  per-conv split weights + BLS (re-generated per conv;
  //                              dead whenever XC5/BIASRELU-XL are live)
  //  RPBT [102107136,102238208)
  char* ws = (char*)d_ws;
  float* R1   = (float*)(ws + 0);
  float* R2   = (float*)(ws + 33554432);
  float* R3   = (float*)(ws + 67108864);
  float* C1   = R3;
  float* C2   = (float*)(ws + 83623936);
  float* XC5  = (float*)(ws + 100139008);
  float* RPBT = (float*)(ws + 102107136);
  u16* XH_A = (u16*)(ws + 33554432);
  u16* XL_A = (u16*)(ws + 33554432 + 16777216);
  u16* XH_B = (u16*)(ws + 67108864);
  u16* XL_B = (u16*)(ws + 83886080);
  u16* WH   = (u16*)(ws + 100663296);
  u16* WL   = (u16*)(ws + 100745216);
  float* BLS = (float*)(ws + 100827136);

  rpbprep_k<<<128, 256, 0, stream>>>(rpb, relidx, RPBT);

  // 1. LOCAL: bn(conv1x1) + bn(conv3x3) on x -> R1   [MFMA, NT=10 (tap9 = 1x1)]
  wsplit_k<<<144, 256, 0, stream>>>(w_l1, g_l1, WH, WL, 64, 9, 0, 0, 10);
  wsplit_k<<<16, 256, 0, stream>>>(w_l2, g_l2, WH, WL, 64, 1, 0, 9, 10);
  bls_k<<<1, 64, 0, stream>>>(b_l1, b_l2, BLS);
  xsplit_k<128><<<1024, 256, 0, stream>>>(x, XH_A, XL_A);
  convmf_k<M_LOCAL, 10, 128, 128, 1><<<dim3(64, 8), 256, 0, stream>>>(
      XH_A, XL_A, WH, WL, BLS, nullptr, R1);

  // 2. GABOR: valid conv, cos||sin + biases -> R2 (xc0, 126x126)
  wsplit_k<<<72, 256, 0, stream>>>(f_cos, nullptr, WH, WL, 32, 9, 0, 0, 9);
  wsplit_k<<<72, 256, 0, stream>>>(f_sin, nullptr, WH, WL, 32, 9, 32, 0, 9);
  xsplit_k<128><<<1024, 256, 0, stream>>>(R1, XH_B, XL_B);
  convmf_k<M_GABOR, 9, 128, 126, 0><<<dim3(64, 8), 256, 0, stream>>>(
      XH_B, XL_B, WH, WL, gb_b1, gb_b2, R2);

  // 3. fft_h + fw-mix, 2 chunks of 256 planes -> R1 (xc1)
  for (int chunk = 0; chunk < 2; ++chunk) {
    int pb = chunk * 256;
    dft_rows_fwd_k<<<256 * 126, 64, 0, stream>>>(R2, C1, pb);
    dft_cols_fwd_mask_k<<<512, 256, 0, stream>>>(C1, C2);
    dft_cols_inv_k<<<512, 256, 0, stream>>>(C2, C1);
    dft_rows_inv_mix_k<<<256 * 126, 128, 0, stream>>>(C1, R2, gb_w, R1, pb);
  }

  // 4. relu6(bn(conv3x3 w_post)) -> R2 (xc2)
  wsplit_k<<<144, 256, 0, stream>>>(w_post, g_post, WH, WL, 64, 9, 0, 0, 9);
  xsplit_k<126><<<1008, 256, 0, stream>>>(R1, XH_B, XL_B);
  convmf_k<M_BNRELU6, 9, 126, 126, 1><<<dim3(64, 8), 256, 0, stream>>>(
      XH_B, XL_B, WH, WL, b_post, nullptr, R2);

  // 5. maxpool 2x2 s1 -> R1 (125^2)
  mp1_k<<<31250, 256, 0, stream>>>(R2, R1);
  // 6. relu(conv3x3 s2 w_gc) -> R3 (62^2)
  convgc_t<<<dim3(16, 8, 2), 256, 0, stream>>>(R1, w_gc, b_gc, R3);
  // 7. maxpool 2x2 s2 -> XC5 (31^2)
  mp2_k<<<1922, 256, 0, stream>>>(R3, XC5);
  // 8. bilinear resize 31 -> 128 -> R1 (xc6)
  resize_k<<<32768, 256, 0, stream>>>(XC5, R1);

  // 9. relu(conv3x3 w_gc1 + b) -> R2 (xc7)
  wsplit_k<<<144, 256, 0, stream>>>(w_gc1, nullptr, WH, WL, 64, 9, 0, 0, 9);
  xsplit_k<128><<<1024, 256, 0, stream>>>(R1, XH_B, XL_B);
  convmf_k<M_BIASRELU, 9, 128, 128, 1><<<dim3(64, 8), 256, 0, stream>>>(
      XH_B, XL_B, WH, WL, b_gc1, nullptr, R2);

  // 10. 1x1 conv w_gc2 + log_softmax -> R1 (local)
  pwlsm_k<<<512, 256, 0, stream>>>(R2, w_gc2, b_gc2, R1);
  // 11. window attention -> R2 (o)
  attn_w_k<<<2048, 256, 0, stream>>>(x, w_qkv, RPBT, R2);
  // 12. ox + oy + local -> R3 (out0)
  avgadd_k<<<32768, 256, 0, stream>>>(R2, R1, R3);
  // 13. depthwise 8x8 + bn -> R2
  dw_k<<<dim3(8, 8, 512), 256, 0, stream>>>(R3, w_dw, g_proj, b_proj, R2);
  // 14. 1x1 conv w_pw -> d_out
  pw_k<<<512, 256, 0, stream>>>(R2, w_pw, out);
  (void)in_sizes; (void)n_in; (void)out_size; (void)ws_size;
}

// Round 3
// 1129.893 us; speedup vs baseline: 1.7120x; 1.1142x over previous
//
#include <hip/hip_runtime.h>
#include <math.h>

#define BN_SC 0.9999950000375f
#define P2N   (6.283185307179586f / 126.f)
#define ATT_SCALE 0.35355339059327373f

typedef float v4f __attribute__((ext_vector_type(4)));
typedef short bf16x8 __attribute__((ext_vector_type(8)));
typedef float f32x4 __attribute__((ext_vector_type(4)));
typedef unsigned short u16;

enum { M_LOCAL = 0, M_GABOR = 1, M_BNRELU6 = 2, M_BIASRELU = 3 };

__device__ __forceinline__ u16 f2bf(float f) {
  unsigned u = __float_as_uint(f);
  return (u16)((u + 0x7FFFu + ((u >> 16) & 1u)) >> 16);
}
__device__ __forceinline__ float bf2f(u16 h) {
  return __uint_as_float(((unsigned)h) << 16);
}

// ------------- rpb bias pre-gather: rpbt[h][j*64+i] = rpb[relidx[i*64+j]*8+h] -------------
__global__ __launch_bounds__(256) void rpbprep_k(
    const float* __restrict__ rpb, const int* __restrict__ relidx, float* __restrict__ rpbt)
{
  int idx = blockIdx.x * 256 + threadIdx.x; // 32768
  int h = idx >> 12, r = idx & 4095, j = r >> 6, i = r & 63;
  rpbt[idx] = rpb[relidx[i * 64 + j] * 8 + h];
}

// ---------------- bias add (local branch: b_l1 + b_l2) ----------------
__global__ void bls_k(const float* __restrict__ a, const float* __restrict__ b,
                      float* __restrict__ o)
{ int i = threadIdx.x; o[i] = a[i] + b[i]; }

// -------- weight split: fp32 [nco][64][ntap] -> bf16 hi/lo [co_off+co][NT][64] --------
// Optional per-co scale (g * BN_SC) folded in.
__global__ __launch_bounds__(256)
void wsplit_k(const float* __restrict__ w, const float* __restrict__ gsc,
              u16* __restrict__ wh, u16* __restrict__ wl,
              int nco, int ntap, int co_off, int tap_off, int NT)
{
  int i = blockIdx.x * 256 + threadIdx.x;
  if (i >= nco * 64 * ntap) return;
  int t = i % ntap, q = i / ntap;
  int cin = q & 63, co = q >> 6;
  float v = w[i];
  if (gsc) v *= gsc[co_off + co] * BN_SC;
  u16 h = f2bf(v);
  u16 l = f2bf(v - bf2f(h));
  int dst = ((co_off + co) * NT + tap_off + t) * 64 + cin;
  wh[dst] = h; wl[dst] = l;
}

// -------- weight split for stride-2 conv, phase-grouped tap order --------
// tap order: [(0,0),(0,2),(2,0),(2,2)], [(0,1),(2,1)], [(1,0),(1,2)], [(1,1)]
__global__ __launch_bounds__(256)
void wsplit_gc_k(const float* __restrict__ w, u16* __restrict__ wh, u16* __restrict__ wl)
{
  int i = blockIdx.x * 256 + threadIdx.x;   // 64*64*9 = 36864
  if (i >= 36864) return;
  int t = i % 9, q = i / 9;
  int cin = q & 63, co = q >> 6;
  const int POS[9] = {0, 4, 1, 6, 8, 7, 2, 5, 3};  // pos_of_tap
  float v = w[i];
  u16 h = f2bf(v);
  u16 l = f2bf(v - bf2f(h));
  int dst = (co * 9 + POS[t]) * 64 + cin;
  wh[dst] = h; wl[dst] = l;
}

// -------- input split+transpose: fp32 NCHW [8][64][HW][HW] -> bf16 hi/lo NHWC --------
template<int HW>
__global__ __launch_bounds__(256)
void xsplit_k(const float* __restrict__ in, u16* __restrict__ xh, u16* __restrict__ xl)
{
  __shared__ float t[64 * (HW + 1)];
  const int by = blockIdx.x;          // b*HW + y
  const int tid = threadIdx.x;
  const int b = by / HW, y = by - b * HW;
  const float* ip = in + (size_t)b * 64 * HW * HW + (size_t)y * HW;
  for (int e = tid; e < 64 * HW; e += 256) {
    int cin = e / HW, x = e - cin * HW;
    t[cin * (HW + 1) + x] = ip[(size_t)cin * HW * HW + x];
  }
  __syncthreads();
  u16* oh = xh + (size_t)by * HW * 64;
  u16* ol = xl + (size_t)by * HW * 64;
  for (int e = tid; e < 64 * HW; e += 256) {
    int x = e >> 6, cin = e & 63;
    float v = t[cin * (HW + 1) + x];
    u16 h = f2bf(v);
    oh[e] = h;
    ol[e] = f2bf(v - bf2f(h));
  }
}

// -------- fused maxpool(2x2,s1) + stride-2 phase split: 126^2 fp32 -> 4x 63^2 bf16 NHWC --------
// Phase plane (py,px): element (u,v) = maxpool_out(2u+py, 2v+px); zero-padded to 63x63.
__global__ __launch_bounds__(256)
void mpsplit_k(const float* __restrict__ in, u16* __restrict__ ph_h, u16* __restrict__ ph_l)
{
  __shared__ float rm[126 * 65];      // [col][cin], pitch 65: rowmax of 2 input rows
  const int tid = threadIdx.x;
  const int bx = blockIdx.x;          // b*126 + py*63 + u
  const int b = bx / 126, r = bx % 126;
  const int py = r / 63, u = r % 63;
  const bool valid_u = !(py == 1 && u == 62);
  if (valid_u) {
    const int r0 = 2 * u + py;
    const float* ip = in + (size_t)b * 64 * 15876;
    for (int e = tid; e < 64 * 126; e += 256) {
      int cin = e / 126, col = e - cin * 126;
      const float* p = ip + (size_t)cin * 15876 + (size_t)r0 * 126 + col;
      rm[col * 65 + cin] = fmaxf(p[0], p[126]);
    }
  }
  __syncthreads();
  for (int e = tid; e < 8064; e += 256) {   // 2 px * 63 v * 64 cin
    int px = e >> 12;                        // e/4096? no: use div
    px = e / 4032;
    int rr = e - px * 4032;
    int v = rr >> 6, cin = rr & 63;
    float val = 0.f;
    if (valid_u && !(px == 1 && v == 62)) {
      int c0 = 2 * v + px;
      val = fmaxf(rm[c0 * 65 + cin], rm[(c0 + 1) * 65 + cin]);
    }
    u16 h = f2bf(val);
    size_t dst = (((size_t)(b * 4 + py * 2 + px) * 63 + u) * 63 + v) * 64 + cin;
    ph_h[dst] = h;
    ph_l[dst] = f2bf(val - bf2f(h));
  }
}

// ================= MFMA conv3x3 (split-bf16, 3-MFMA fp32-accurate) =================
// Block: 16x16 output pixels x 64 co. 4 waves = 2(co half) x 2(8-row half).
// LDS: 18x18 halo, per pixel-row 144 B = [hi 4x16B][lo 4x16B][16B pad].
// A (weights) read from global (L2-hot), layout [co][NT][64cin] bf16, prefetched per tap.
// NT=10 for LOCAL (tap 9 = fused 1x1 at center), else 9.
template<int MODE, int NT, int IN_HW, int OUT_HW, int PAD>
__global__ __launch_bounds__(256, 3)
void convmf_k(const u16* __restrict__ xh, const u16* __restrict__ xl,
              const u16* __restrict__ wh, const u16* __restrict__ wl,
              const float* __restrict__ ba, const float* __restrict__ bb,
              float* __restrict__ out)
{
  __shared__ uint4 lds4[2916];               // 324 * 144 B = 46656
  char* lds = (char*)lds4;
  const int tid = threadIdx.x;
  const int lane = tid & 63;
  const int wv = __builtin_amdgcn_readfirstlane(tid >> 6);
  const int wco = wv & 1, wpx = wv >> 1;
  const int b = blockIdx.y;
  const int oy0 = (blockIdx.x >> 3) * 16, ox0 = (blockIdx.x & 7) * 16;
  const int iy0 = oy0 - PAD, ix0 = ox0 - PAD;
  const int l15 = lane & 15, l4 = lane >> 4;
  const int bboff = l15 * 144 + l4 * 16;
  const int aoff  = l15 * (NT * 64) + l4 * 8;
  const u16* wh0 = wh + wco * 32 * NT * 64 + aoff;
  const u16* wl0 = wl + wco * 32 * NT * 64 + aoff;

  f32x4 acc[2][8];
#pragma unroll
  for (int f = 0; f < 2; ++f)
#pragma unroll
    for (int r = 0; r < 8; ++r) { f32x4 z = {0.f, 0.f, 0.f, 0.f}; acc[f][r] = z; }

#pragma unroll 1
  for (int cc = 0; cc < 64; cc += 32) {
    __syncthreads();
    // stage 18x18 halo, cin chunk [cc, cc+32): hi and lo, 16B per (pixel, part)
    for (int e = tid; e < 2592; e += 256) {
      int pix = e >> 3, part = e & 7;
      int lr = pix / 18, lc = pix - lr * 18;
      int iy = iy0 + lr, ix = ix0 + lc;
      uint4 v = make_uint4(0u, 0u, 0u, 0u);
      if ((unsigned)iy < (unsigned)IN_HW && (unsigned)ix < (unsigned)IN_HW) {
        const u16* s = ((part < 4) ? xh : xl)
            + ((size_t)(b * IN_HW + iy) * IN_HW + ix) * 64 + cc + (part & 3) * 8;
        v = *(const uint4*)s;
      }
      *(uint4*)(lds + pix * 144 + part * 16) = v;
    }
    __syncthreads();

    // A frags for tap 0
    bf16x8 ah0 = *(const bf16x8*)(wh0 + cc);
    bf16x8 al0 = *(const bf16x8*)(wl0 + cc);
    bf16x8 ah1 = *(const bf16x8*)(wh0 + 16 * NT * 64 + cc);
    bf16x8 al1 = *(const bf16x8*)(wl0 + 16 * NT * 64 + cc);

#pragma unroll 1
    for (int t = 0; t < NT; ++t) {
      // prefetch next tap's A frags (L2-hot global)
      int tn = (t + 1 < NT) ? t + 1 : t;
      bf16x8 nh0 = *(const bf16x8*)(wh0 + tn * 64 + cc);
      bf16x8 nl0 = *(const bf16x8*)(wl0 + tn * 64 + cc);
      bf16x8 nh1 = *(const bf16x8*)(wh0 + 16 * NT * 64 + tn * 64 + cc);
      bf16x8 nl1 = *(const bf16x8*)(wl0 + 16 * NT * 64 + tn * 64 + cc);
      int te = (t >= 9) ? 4 : t;            // tap 9 (1x1) = center (1,1)
      int dy = te / 3;
      int dx = te - dy * 3;
      const char* pb = lds + ((wpx * 8 + dy) * 18 + dx) * 144 + bboff;
#pragma unroll
      for (int r = 0; r < 8; ++r) {
        bf16x8 bh = *(const bf16x8*)(pb + r * 2592);
        bf16x8 bl = *(const bf16x8*)(pb + r * 2592 + 64);
        acc[0][r] = __builtin_amdgcn_mfma_f32_16x16x32_bf16(ah0, bh, acc[0][r], 0, 0, 0);
        acc[1][r] = __builtin_amdgcn_mfma_f32_16x16x32_bf16(ah1, bh, acc[1][r], 0, 0, 0);
        acc[0][r] = __builtin_amdgcn_mfma_f32_16x16x32_bf16(ah0, bl, acc[0][r], 0, 0, 0);
        acc[0][r] = __builtin_amdgcn_mfma_f32_16x16x32_bf16(al0, bh, acc[0][r], 0, 0, 0);
        acc[1][r] = __builtin_amdgcn_mfma_f32_16x16x32_bf16(ah1, bl, acc[1][r], 0, 0, 0);
        acc[1][r] = __builtin_amdgcn_mfma_f32_16x16x32_bf16(al1, bh, acc[1][r], 0, 0, 0);
      }
      ah0 = nh0; al0 = nl0; ah1 = nh1; al1 = nl1;
    }
  }

  // ---- epilogue: C/D frag (col = lane&15 -> pixel x, row = (lane>>4)*4+j -> co) ----
  const int ox = ox0 + l15;
#pragma unroll
  for (int f = 0; f < 2; ++f) {
    const int cb = wco * 32 + f * 16 + l4 * 4;
    float bias[4];
#pragma unroll
    for (int j = 0; j < 4; ++j) {
      int c = cb + j;
      bias[j] = (MODE == M_GABOR && c >= 32) ? bb[c - 32] : ba[c];
    }
#pragma unroll
    for (int r = 0; r < 8; ++r) {
      int oy = oy0 + wpx * 8 + r;
      if (OUT_HW != 128 && (oy >= OUT_HW || ox >= OUT_HW)) continue;
#pragma unroll
      for (int j = 0; j < 4; ++j) {
        float v = acc[f][r][j] + bias[j];
        if (MODE == M_BNRELU6) v = fminf(fmaxf(v, 0.f), 6.f);
        if (MODE == M_BIASRELU) v = fmaxf(v, 0.f);
        out[(((size_t)(b * 64) + cb + j) * OUT_HW + oy) * OUT_HW + ox] = v;
      }
    }
  }
}

// ======= MFMA stride-2 conv3x3 via polyphase planes (split-bf16), + bias + relu =======
// Block: 8x8 output pixels x 64 co, 4 waves = 2(co) x 2(row-half). Output 62x62.
// Per phase: stage 9x9 halo (32 cin chunk, hi+lo) -> taps of that phase.
__global__ __launch_bounds__(256)
void convgc_mf(const u16* __restrict__ ph_h, const u16* __restrict__ ph_l,
               const u16* __restrict__ wh, const u16* __restrict__ wl,
               const float* __restrict__ bias, float* __restrict__ out)
{
  __shared__ char lds[81 * 144];             // 11664 B
  const int tid = threadIdx.x;
  const int lane = tid & 63;
  const int wv = __builtin_amdgcn_readfirstlane(tid >> 6);
  const int wco = wv & 1, wpx = wv >> 1;
  const int b = blockIdx.y;
  const int oy0 = (blockIdx.x >> 3) * 8, ox0 = (blockIdx.x & 7) * 8;
  const int l15 = lane & 15, l4 = lane >> 4;
  const int pr_ = l15 >> 3, pc_ = l15 & 7;
  const int aoff = l15 * 576 + l4 * 8;       // 9 taps * 64 cin
  const u16* wh0 = wh + wco * 32 * 576 + aoff;
  const u16* wl0 = wl + wco * 32 * 576 + aoff;

  f32x4 acc[2][2];
#pragma unroll
  for (int f = 0; f < 2; ++f)
#pragma unroll
    for (int g = 0; g < 2; ++g) { f32x4 z = {0.f, 0.f, 0.f, 0.f}; acc[f][g] = z; }

  const int PHA[9] = {0, 0, 0, 0, 1, 1, 2, 2, 3};
  const int OYO[9] = {0, 0, 1, 1, 0, 1, 0, 0, 0};
  const int OXO[9] = {0, 1, 0, 1, 0, 0, 0, 1, 0};

#pragma unroll 1
  for (int cc = 0; cc < 64; cc += 32) {
#pragma unroll
    for (int pos = 0; pos < 9; ++pos) {
      const int ph = PHA[pos];
      if (pos == 0 || pos == 4 || pos == 6 || pos == 8) {
        __syncthreads();
        // stage 9x9 halo of phase plane ph, cin chunk [cc,cc+32): hi+lo
        for (int e = tid; e < 648; e += 256) {
          int pix = e >> 3, part = e & 7;
          int pu = pix / 9, pv = pix - pu * 9;
          int u = oy0 + pu, v = ox0 + pv;
          uint4 val = make_uint4(0u, 0u, 0u, 0u);
          if (u < 63 && v < 63) {
            const u16* s = ((part < 4) ? ph_h : ph_l)
                + (((size_t)(b * 4 + ph) * 63 + u) * 63 + v) * 64 + cc + (part & 3) * 8;
            val = *(const uint4*)s;
          }
          *(uint4*)(lds + pix * 144 + part * 16) = val;
        }
        __syncthreads();
      }
      bf16x8 ah0 = *(const bf16x8*)(wh0 + pos * 64 + cc);
      bf16x8 al0 = *(const bf16x8*)(wl0 + pos * 64 + cc);
      bf16x8 ah1 = *(const bf16x8*)(wh0 + 16 * 576 + pos * 64 + cc);
      bf16x8 al1 = *(const bf16x8*)(wl0 + 16 * 576 + pos * 64 + cc);
#pragma unroll
      for (int g = 0; g < 2; ++g) {
        const int lrow = wpx * 4 + g * 2 + pr_ + OYO[pos];
        const int lcol = pc_ + OXO[pos];
        const char* pb = lds + (lrow * 9 + lcol) * 144 + l4 * 16;
        bf16x8 bh = *(const bf16x8*)pb;
        bf16x8 bl = *(const bf16x8*)(pb + 64);
        acc[0][g] = __builtin_amdgcn_mfma_f32_16x16x32_bf16(ah0, bh, acc[0][g], 0, 0, 0);
        acc[1][g] = __builtin_amdgcn_mfma_f32_16x16x32_bf16(ah1, bh, acc[1][g], 0, 0, 0);
        acc[0][g] = __builtin_amdgcn_mfma_f32_16x16x32_bf16(ah0, bl, acc[0][g], 0, 0, 0);
        acc[0][g] = __builtin_amdgcn_mfma_f32_16x16x32_bf16(al0, bh, acc[0][g], 0, 0, 0);
        acc[1][g] = __builtin_amdgcn_mfma_f32_16x16x32_bf16(ah1, bl, acc[1][g], 0, 0, 0);
        acc[1][g] = __builtin_amdgcn_mfma_f32_16x16x32_bf16(al1, bh, acc[1][g], 0, 0, 0);
      }
    }
  }

  // epilogue: col = lane&15 -> pixel (2 rows x 8 cols), row = l4*4+j -> co
  const int ox = ox0 + pc_;
#pragma unroll
  for (int f = 0; f < 2; ++f) {
    const int cb = wco * 32 + f * 16 + l4 * 4;
#pragma unroll
    for (int g = 0; g < 2; ++g) {
      int oy = oy0 + wpx * 4 + g * 2 + pr_;
      if (oy >= 62 || ox >= 62) continue;
#pragma unroll
      for (int j = 0; j < 4; ++j) {
        float v = acc[f][g][j] + bias[cb + j];
        out[(((size_t)(b * 64) + cb + j) * 62 + oy) * 62 + ox] = fmaxf(v, 0.f);
      }
    }
  }
}

// ======================= DFT (126-pt), table-based, Hermitian-half =======================

__global__ __launch_bounds__(64)
void dft_rows_fwd_k(const float* __restrict__ in, float* __restrict__ outC, int planeBase)
{
  __shared__ float2 r2[63];
  __shared__ float2 T[126];
  const int lp = blockIdx.x / 126, n1 = blockIdx.x % 126;
  const int tid = threadIdx.x;
  const float2* row = (const float2*)(in + (size_t)(planeBase + lp) * 15876 + (size_t)n1 * 126);
  if (tid < 63) r2[tid] = row[tid];
  for (int e = tid; e < 126; e += 64) { float s, c; sincosf(P2N * (float)e, &s, &c); T[e] = make_float2(c, s); }
  __syncthreads();
  const int k2 = tid;
  const int inc = (2 * k2) % 126;
  int m = 0;
  float Er = 0.f, Ei = 0.f, Or = 0.f, Oi = 0.f;
  for (int n = 0; n < 63; ++n) {
    float2 rv = r2[n];
    float2 t = T[m];
    Er += rv.x * t.x; Ei -= rv.x * t.y;
    Or += rv.y * t.x; Oi -= rv.y * t.y;
    m += inc; if (m >= 126) m -= 126;
  }
  float c = T[k2].x, s = T[k2].y;
  float2* o = (float2*)(outC + (size_t)lp * 16128 + (size_t)n1 * 128);
  o[k2] = make_float2(Er + c * Or + s * Oi, Ei + c * Oi - s * Or);
}

__global__ __launch_bounds__(256)
void dft_cols_fwd_mask_k(const float* __restrict__ inC, float* __restrict__ outC)
{
  __shared__ float2 S[4032];
  __shared__ float2 T[126];
  const int lp = blockIdx.x >> 1, gbase = (blockIdx.x & 1) * 32;
  const int tid = threadIdx.x;
  if (tid < 126) { float s, c; sincosf(P2N * (float)tid, &s, &c); T[tid] = make_float2(c, s); }
  const float2* src = (const float2*)(inC + (size_t)lp * 16128);
  for (int e = tid; e < 4032; e += 256) {
    int n1 = e >> 5, c = e & 31;
    S[e] = src[n1 * 64 + gbase + c];
  }
  __syncthreads();
  float2* dst = (float2*)(outC + (size_t)lp * 16128);
  for (int e = tid; e < 2016; e += 256) {
    int k1 = e >> 5, c = e & 31;
    int k2 = gbase + c;
    int inc = 2 * k1;
    int me = 0, mo = k1;
    float Er = 0.f, Ei = 0.f, Or = 0.f, Oi = 0.f;
    for (int u = 0; u < 63; ++u) {
      float2 s0 = S[(2 * u) * 32 + c];
      float2 t0 = T[me];
      Er += s0.x * t0.x + s0.y * t0.y;
      Ei += s0.y * t0.x - s0.x * t0.y;
      float2 s1 = S[(2 * u + 1) * 32 + c];
      float2 t1 = T[mo];
      Or += s1.x * t1.x + s1.y * t1.y;
      Oi += s1.y * t1.x - s1.x * t1.y;
      me += inc; if (me >= 126) me -= 126;
      mo += inc; if (mo >= 126) mo -= 126;
    }
    int f2 = (k2 <= 62) ? k2 : k2 - 126;
    float ar = Er + Or, ai = Ei + Oi;
    float br = Er - Or, bi = Ei - Oi;
    float sa = (k1 * k1 + f2 * f2 > 1600) ? sqrtf(ar * ar + ai * ai) * (1.f / 15876.f) : 0.f;
    int f1b = k1 - 63;
    float sb = (f1b * f1b + f2 * f2 > 1600) ? sqrtf(br * br + bi * bi) * (1.f / 15876.f) : 0.f;
    dst[(size_t)k1 * 64 + k2]        = make_float2(ar * sa, ai * sa);
    dst[(size_t)(k1 + 63) * 64 + k2] = make_float2(br * sb, bi * sb);
  }
}

__global__ __launch_bounds__(256)
void dft_cols_inv_k(const float* __restrict__ inC, float* __restrict__ outC)
{
  __shared__ float2 S[4032];
  __shared__ float2 T[126];
  const int lp = blockIdx.x >> 1, gbase = (blockIdx.x & 1) * 32;
  const int tid = threadIdx.x;
  if (tid < 126) { float s, c; sincosf(P2N * (float)tid, &s, &c); T[tid] = make_float2(c, s); }
  const float2* src = (const float2*)(inC + (size_t)lp * 16128);
  for (int e = tid; e < 4032; e += 256) {
    int k1 = e >> 5, c = e & 31;
    S[e] = src[k1 * 64 + gbase + c];
  }
  __syncthreads();
  float2* dst = (float2*)(outC + (size_t)lp * 16128);
  for (int e = tid; e < 2016; e += 256) {
    int n1 = e >> 5, c = e & 31;
    int k2 = gbase + c;
    int inc = (2 * n1) % 126;
    int me = 0, mo = n1;
    float Er = 0.f, Ei = 0.f, Or = 0.f, Oi = 0.f;
    for (int u = 0; u < 63; ++u) {
      float2 s0 = S[(2 * u) * 32 + c];
      float2 t0 = T[me];
      Er += s0.x * t0.x - s0.y * t0.y;
      Ei += s0.x * t0.y + s0.y * t0.x;
      float2 s1 = S[(2 * u + 1) * 32 + c];
      float2 t1 = T[mo];
      Or += s1.x * t1.x - s1.y * t1.y;
      Oi += s1.x * t1.y + s1.y * t1.x;
      me += inc; if (me >= 126) me -= 126;
      mo += inc; if (mo >= 126) mo -= 126;
    }
    dst[(size_t)n1 * 64 + k2]        = make_float2(Er + Or, Ei + Oi);
    dst[(size_t)(n1 + 63) * 64 + k2] = make_float2(Er - Or, Ei - Oi);
  }
}

__global__ __launch_bounds__(128)
void dft_rows_inv_mix_k(const float* __restrict__ inC, const float* __restrict__ xc0,
                        const float* __restrict__ gb_w, float* __restrict__ out, int planeBase)
{
  __shared__ float2 Z[64];
  __shared__ float2 T[126];
  const int lp = blockIdx.x / 126, n1 = blockIdx.x % 126;
  const int tid = threadIdx.x;
  const float2* src = (const float2*)(inC + (size_t)lp * 16128 + (size_t)n1 * 128);
  if (tid < 64) Z[tid] = src[tid];
  if (tid < 126) { float s, c; sincosf(P2N * (float)tid, &s, &c); T[tid] = make_float2(c, s); }
  __syncthreads();
  const int n2 = tid;
  if (n2 < 126) {
    float a = Z[0].x + ((n2 & 1) ? -Z[63].x : Z[63].x);
    float acc = 0.f;
    int m = n2;
    for (int k2 = 1; k2 < 63; ++k2) {
      float2 z = Z[k2];
      float2 t = T[m];
      acc += z.x * t.x - z.y * t.y;
      m += n2; if (m >= 126) m -= 126;
    }
    a += 2.f * acc;
    float w0 = fmaxf(gb_w[0], 0.f), w1 = fmaxf(gb_w[1], 0.f);
    float inv = 1.f / (w0 + w1 + 1e-8f);
    size_t gi = (size_t)(planeBase + lp) * 15876 + (size_t)n1 * 126 + n2;
    out[gi] = (w0 * inv) * fabsf(a) + (w1 * inv) * xc0[gi];
  }
}

// ---------------- maxpool 2x2 stride2: 62 -> 31 ----------------
__global__ __launch_bounds__(256) void mp2_k(const float* __restrict__ in, float* __restrict__ out)
{
  int idx = blockIdx.x * 256 + threadIdx.x;
  if (idx >= 512 * 31 * 31) return;
  int x = idx % 31, y = (idx / 31) % 31, p = idx / 961;
  const float* ip = in + (size_t)p * 3844 + (size_t)(2 * y) * 62 + 2 * x;
  out[idx] = fmaxf(fmaxf(ip[0], ip[1]), fmaxf(ip[62], ip[63]));
}

// ---------------- bilinear resize 31 -> 128 ----------------
__global__ __launch_bounds__(256) void resize_k(const float* __restrict__ in, float* __restrict__ out)
{
  int idx = blockIdx.x * 256 + threadIdx.x;
  if (idx >= 512 * 128 * 128) return;
  int x = idx & 127, y = (idx >> 7) & 127, p = idx >> 14;
  float sy = (y + 0.5f) * (31.f / 128.f) - 0.5f; sy = fminf(fmaxf(sy, 0.f), 30.f);
  float sx = (x + 0.5f) * (31.f / 128.f) - 0.5f; sx = fminf(fmaxf(sx, 0.f), 30.f);
  int y0 = (int)sy; float fy = sy - (float)y0; int y1 = min(y0 + 1, 30);
  int x0 = (int)sx; float fx = sx - (float)x0; int x1 = min(x0 + 1, 30);
  const float* ip = in + (size_t)p * 961;
  float v = (1.f - fy) * ((1.f - fx) * ip[y0 * 31 + x0] + fx * ip[y0 * 31 + x1])
          + fy         * ((1.f - fx) * ip[y1 * 31 + x0] + fx * ip[y1 * 31 + x1]);
  out[idx] = v;
}

// ---------------- 1x1 conv (w_gc2 + bias) + log_softmax over 64 channels ----------------
__global__ __launch_bounds__(256)
void pwlsm_k(const float* __restrict__ in, const float* __restrict__ w,
             const float* __restrict__ bias, float* __restrict__ out)
{
  __shared__ float zs[64 * 256];
  int idx = blockIdx.x * 256 + threadIdx.x;
  int b = idx >> 14, px = idx & 16383;
  const float* ip = in + ((size_t)b << 20) + px;
  float v[64];
#pragma unroll
  for (int i = 0; i < 64; ++i) v[i] = ip[(size_t)i << 14];
  float m = -1e30f;
  for (int co = 0; co < 64; ++co) {
    float s = bias[co];
    const float* wk = w + co * 64;
#pragma unroll
    for (int i = 0; i < 64; ++i) s += v[i] * wk[i];
    zs[co * 256 + threadIdx.x] = s;
    m = fmaxf(m, s);
  }
  float sum = 0.f;
  for (int co = 0; co < 64; ++co) sum += __expf(zs[co * 256 + threadIdx.x] - m);
  float lse = m + __logf(sum);
  float* op = out + ((size_t)b << 20) + px;
  for (int co = 0; co < 64; ++co) op[(size_t)co << 14] = zs[co * 256 + threadIdx.x] - lse;
}

// ---------------- windowed attention: wave-per-head, register softmax ----------------
__global__ __launch_bounds__(256)
void attn_w_k(const float* __restrict__ x, const float* __restrict__ wqkv,
              const float* __restrict__ rpbt, float* __restrict__ o_out)
{
  __shared__ float xt[4096];            // [cin][pix] 16 KB
  __shared__ float kvb[4][2][64][8];    // [wave][k|v][j][d] 16 KB
  const int tid = threadIdx.x;
  const int lane = tid & 63;
  const int wv = __builtin_amdgcn_readfirstlane(tid >> 6);
  const int b = blockIdx.x >> 8, gy = (blockIdx.x >> 4) & 15, gx = blockIdx.x & 15;
  const int y0 = gy * 8, x0 = gx * 8;

  for (int e = tid; e < 4096; e += 256) {
    int cin = e >> 6, pix = e & 63;
    xt[e] = x[((size_t)(b * 64 + cin) * 128 + (y0 + (pix >> 3))) * 128 + x0 + (pix & 7)];
  }
  __syncthreads();

  const int row = y0 + (lane >> 3), col = x0 + (lane & 7);

  for (int hh = 0; hh < 2; ++hh) {
    const int h = hh * 4 + wv;      // wave-uniform
    const float* wq = wqkv + (size_t)(h * 8) * 64;
    const float* wk = wqkv + (size_t)(64 + h * 8) * 64;
    const float* wvv = wqkv + (size_t)(128 + h * 8) * 64;
    float q[8], kk[8], vv[8];
#pragma unroll
    for (int d = 0; d < 8; ++d) { q[d] = 0.f; kk[d] = 0.f; vv[d] = 0.f; }
    for (int cb = 0; cb < 64; cb += 4) {
      float xv0 = xt[(cb + 0) * 64 + lane];
      float xv1 = xt[(cb + 1) * 64 + lane];
      float xv2 = xt[(cb + 2) * 64 + lane];
      float xv3 = xt[(cb + 3) * 64 + lane];
#pragma unroll
      for (int d = 0; d < 8; ++d) {
        float4 a = *(const float4*)(wq + d * 64 + cb);
        q[d] += xv0 * a.x + xv1 * a.y + xv2 * a.z + xv3 * a.w;
        float4 bq = *(const float4*)(wk + d * 64 + cb);
        kk[d] += xv0 * bq.x + xv1 * bq.y + xv2 * bq.z + xv3 * bq.w;
        float4 cq = *(const float4*)(wvv + d * 64 + cb);
        vv[d] += xv0 * cq.x + xv1 * cq.y + xv2 * cq.z + xv3 * cq.w;
      }
    }
#pragma unroll
    for (int d = 0; d < 8; ++d) {
      kvb[wv][0][lane][d] = kk[d];
      kvb[wv][1][lane][d] = vv[d];
    }
    __syncthreads();

    const float* rb = rpbt + h * 4096;
    float P[64];
    float m = -1e30f;
#pragma unroll
    for (int j = 0; j < 64; ++j) {
      float4 k0 = *(const float4*)&kvb[wv][0][j][0];
      float4 k1 = *(const float4*)&kvb[wv][0][j][4];
      float s = q[0] * k0.x + q[1] * k0.y + q[2] * k0.z + q[3] * k0.w
              + q[4] * k1.x + q[5] * k1.y + q[6] * k1.z + q[7] * k1.w;
      s = s * ATT_SCALE + rb[j * 64 + lane];
      P[j] = s;
      m = fmaxf(m, s);
    }
    float sum = 0.f;
#pragma unroll
    for (int j = 0; j < 64; ++j) { float p = __expf(P[j] - m); P[j] = p; sum += p; }
    float inv = 1.f / sum;

    float acc[8];
#pragma unroll
    for (int d = 0; d < 8; ++d) acc[d] = 0.f;
#pragma unroll
    for (int j = 0; j < 64; ++j) {
      float p = P[j];
      float4 v0 = *(const float4*)&kvb[wv][1][j][0];
      float4 v1 = *(const float4*)&kvb[wv][1][j][4];
      acc[0] += p * v0.x; acc[1] += p * v0.y; acc[2] += p * v0.z; acc[3] += p * v0.w;
      acc[4] += p * v1.x; acc[5] += p * v1.y; acc[6] += p * v1.z; acc[7] += p * v1.w;
    }
#pragma unroll
    for (int d = 0; d < 8; ++d)
      o_out[((size_t)(b * 64 + h * 8 + d) * 128 + row) * 128 + col] = acc[d] * inv;
    __syncthreads();
  }
}

// ------- directional avg pools (reflect+zero pad semantics) + add local -------
__global__ __launch_bounds__(256)
void avgadd_k(const float* __restrict__ o, const float* __restrict__ loc, float* __restrict__ out)
{
  int idx = blockIdx.x * 256 + threadIdx.x;
  if (idx >= 8388608) return;
  int x = idx & 127, y = (idx >> 7) & 127;
  size_t p = (size_t)(idx >> 14);
  const float* op = o + (p << 14);
  float s1 = 0.f, s2 = 0.f;
#pragma unroll
  for (int t = 0; t < 8; ++t) {
    int r = y - 3 + t;
    if (r >= 0 && r <= 128) { int rr = (r == 128) ? 126 : r; s1 += op[rr * 128 + x]; }
    int cc = x - 3 + t;
    if (cc >= 0 && cc <= 128) { int ss = (cc == 128) ? 126 : cc; s2 += op[y * 128 + ss]; }
  }
  out[idx] = 0.125f * (s1 + s2) + loc[idx];
}

// ---------------- depthwise 8x8 conv (pad_out + pad3, zero) + BN ----------------
__global__ __launch_bounds__(256)
void dw_k(const float* __restrict__ in, const float* __restrict__ w,
          const float* __restrict__ g, const float* __restrict__ bb, float* __restrict__ out)
{
  __shared__ float t[23 * 23];
  const int tid = threadIdx.x;
  const int tx = tid & 15, ty = tid >> 4;
  const int x0 = blockIdx.x * 16, y0 = blockIdx.y * 16;
  const int pc = blockIdx.z;
  const int c = pc & 63;
  const float* ip = in + (size_t)pc * 16384;
  for (int e = tid; e < 529; e += 256) {
    int yy = e / 23, xx = e % 23;
    int iy = y0 + yy - 3, ix = x0 + xx - 3;
    t[e] = (iy >= 0 && iy < 128 && ix >= 0 && ix < 128) ? ip[iy * 128 + ix] : 0.f;
  }
  __syncthreads();
  const float* wk = w + c * 64;
  float s = 0.f;
#pragma unroll
  for (int ky = 0; ky < 8; ++ky)
#pragma unroll
    for (int kx = 0; kx < 8; ++kx)
      s += t[(ty + ky) * 23 + tx + kx] * wk[ky * 8 + kx];
  out[(size_t)pc * 16384 + (y0 + ty) * 128 + x0 + tx] = s * (g[c] * BN_SC) + bb[c];
}

// ---------------- final 1x1 conv (w_pw, no bias) ----------------
__global__ __launch_bounds__(256)
void pw_k(const float* __restrict__ in, const float* __restrict__ w, float* __restrict__ out)
{
  int idx = blockIdx.x * 256 + threadIdx.x;
  int b = idx >> 14, px = idx & 16383;
  const float* ip = in + ((size_t)b << 20) + px;
  float v[64];
#pragma unroll
  for (int i = 0; i < 64; ++i) v[i] = ip[(size_t)i << 14];
  float* op = out + ((size_t)b << 20) + px;
  for (int co = 0; co < 64; ++co) {
    const float* wk = w + co * 64;
    float s = 0.f;
#pragma unroll
    for (int i = 0; i < 64; ++i) s += v[i] * wk[i];
    op[(size_t)co << 14] = s;
  }
}

// =======================================================================
extern "C" void kernel_launch(void* const* d_in, const int* in_sizes, int n_in,
                              void* d_out, int out_size, void* d_ws, size_t ws_size,
                              hipStream_t stream)
{
  const float* x      = (const float*)d_in[0];
  const float* w_qkv  = (const float*)d_in[1];
  const float* w_l1   = (const float*)d_in[2];
  const float* g_l1   = (const float*)d_in[3];
  const float* b_l1   = (const float*)d_in[4];
  const float* w_l2   = (const float*)d_in[5];
  const float* g_l2   = (const float*)d_in[6];
  const float* b_l2   = (const float*)d_in[7];
  const float* f_cos  = (const float*)d_in[8];
  const float* f_sin  = (const float*)d_in[9];
  const float* gb_b1  = (const float*)d_in[10];
  const float* gb_b2  = (const float*)d_in[11];
  const float* gb_w   = (const float*)d_in[12];
  const float* w_post = (const float*)d_in[13];
  const float* g_post = (const float*)d_in[14];
  const float* b_post = (const float*)d_in[15];
  const float* w_gc   = (const float*)d_in[16];
  const float* b_gc   = (const float*)d_in[17];
  const float* w_gc1  = (const float*)d_in[18];
  const float* b_gc1  = (const float*)d_in[19];
  const float* w_gc2  = (const float*)d_in[20];
  const float* b_gc2  = (const float*)d_in[21];
  const float* rpb    = (const float*)d_in[22];
  const float* w_dw   = (const float*)d_in[23];
  const float* g_proj = (const float*)d_in[24];
  const float* b_proj = (const float*)d_in[25];
  const float* w_pw   = (const float*)d_in[26];
  const int*   relidx = (const int*)d_in[27];
  float* out = (float*)d_out;

  // Workspace map (within the proven 102,238,208-byte footprint):
  //  R1   [0,        33554432)   fp32 scratch A; also PH_H/PH_L phase planes (steps 5-6)
  //  R2   [33554432, 67108864)   fp32 scratch B; also XH_A/XL_A for LOCAL conv
  //  R3/C1[67108864, 83623936)   FFT C1 / convgc out / out0; also XH_B
  //  C2   [83623936, 100139008)  FFT C2; XL_B starts at 83886080
  //  XC5  [100139008,102107136)  steps mp2->resize only
  //  W    [100663296,100827392)  per-conv split weights + BLS (re-generated per conv)
  //  RPBT [102107136,102238208)
  char* ws = (char*)d_ws;
  float* R1   = (float*)(ws + 0);
  float* R2   = (float*)(ws + 33554432);
  float* R3   = (float*)(ws + 67108864);
  float* C1   = R3;
  float* C2   = (float*)(ws + 83623936);
  float* XC5  = (float*)(ws + 100139008);
  float* RPBT = (float*)(ws + 102107136);
  u16* XH_A = (u16*)(ws + 33554432);
  u16* XL_A = (u16*)(ws + 33554432 + 16777216);
  u16* XH_B = (u16*)(ws + 67108864);
  u16* XL_B = (u16*)(ws + 83886080);
  u16* PH_H = (u16*)(ws + 0);                 // 16,257,024 B (8b x 4ph x 63x63 x 64c)
  u16* PH_L = (u16*)(ws + 16257024);          // ends 32,514,048 < 33,554,432
  u16* WH   = (u16*)(ws + 100663296);
  u16* WL   = (u16*)(ws + 100745216);
  float* BLS = (float*)(ws + 100827136);

  rpbprep_k<<<128, 256, 0, stream>>>(rpb, relidx, RPBT);

  // 1. LOCAL: bn(conv1x1) + bn(conv3x3) on x -> R1   [MFMA, NT=10 (tap9 = 1x1)]
  wsplit_k<<<144, 256, 0, stream>>>(w_l1, g_l1, WH, WL, 64, 9, 0, 0, 10);
  wsplit_k<<<16, 256, 0, stream>>>(w_l2, g_l2, WH, WL, 64, 1, 0, 9, 10);
  bls_k<<<1, 64, 0, stream>>>(b_l1, b_l2, BLS);
  xsplit_k<128><<<1024, 256, 0, stream>>>(x, XH_A, XL_A);
  convmf_k<M_LOCAL, 10, 128, 128, 1><<<dim3(64, 8), 256, 0, stream>>>(
      XH_A, XL_A, WH, WL, BLS, nullptr, R1);

  // 2. GABOR: valid conv, cos||sin + biases -> R2 (xc0, 126x126)
  wsplit_k<<<72, 256, 0, stream>>>(f_cos, nullptr, WH, WL, 32, 9, 0, 0, 9);
  wsplit_k<<<72, 256, 0, stream>>>(f_sin, nullptr, WH, WL, 32, 9, 32, 0, 9);
  xsplit_k<128><<<1024, 256, 0, stream>>>(R1, XH_B, XL_B);
  convmf_k<M_GABOR, 9, 128, 126, 0><<<dim3(64, 8), 256, 0, stream>>>(
      XH_B, XL_B, WH, WL, gb_b1, gb_b2, R2);

  // 3. fft_h + fw-mix, 2 chunks of 256 planes -> R1 (xc1)
  for (int chunk = 0; chunk < 2; ++chunk) {
    int pb = chunk * 256;
    dft_rows_fwd_k<<<256 * 126, 64, 0, stream>>>(R2, C1, pb);
    dft_cols_fwd_mask_k<<<512, 256, 0, stream>>>(C1, C2);
    dft_cols_inv_k<<<512, 256, 0, stream>>>(C2, C1);
    dft_rows_inv_mix_k<<<256 * 126, 128, 0, stream>>>(C1, R2, gb_w, R1, pb);
  }

  // 4. relu6(bn(conv3x3 w_post)) -> R2 (xc2)
  wsplit_k<<<144, 256, 0, stream>>>(w_post, g_post, WH, WL, 64, 9, 0, 0, 9);
  xsplit_k<126><<<1008, 256, 0, stream>>>(R1, XH_B, XL_B);
  convmf_k<M_BNRELU6, 9, 126, 126, 1><<<dim3(64, 8), 256, 0, stream>>>(
      XH_B, XL_B, WH, WL, b_post, nullptr, R2);

  // 5. fused maxpool(2x2 s1) + stride-2 polyphase split -> PH planes (R1 region)
  mpsplit_k<<<1008, 256, 0, stream>>>(R2, PH_H, PH_L);

  // 6. MFMA stride-2 conv w_gc + bias + relu -> R3 (62^2)
  wsplit_gc_k<<<144, 256, 0, stream>>>(w_gc, WH, WL);
  convgc_mf<<<dim3(64, 8), 256, 0, stream>>>(PH_H, PH_L, WH, WL, b_gc, R3);

  // 7. maxpool 2x2 s2 -> XC5 (31^2)
  mp2_k<<<1922, 256, 0, stream>>>(R3, XC5);
  // 8. bilinear resize 31 -> 128 -> R1 (xc6)
  resize_k<<<32768, 256, 0, stream>>>(XC5, R1);

  // 9. relu(conv3x3 w_gc1 + b) -> R2 (xc7)
  wsplit_k<<<144, 256, 0, stream>>>(w_gc1, nullptr, WH, WL, 64, 9, 0, 0, 9);
  xsplit_k<128><<<1024, 256, 0, stream>>>(R1, XH_B, XL_B);
  convmf_k<M_BIASRELU, 9, 128, 128, 1><<<dim3(64, 8), 256, 0, stream>>>(
      XH_B, XL_B, WH, WL, b_gc1, nullptr, R2);

  // 10. 1x1 conv w_gc2 + log_softmax -> R1 (local)
  pwlsm_k<<<512, 256, 0, stream>>>(R2, w_gc2, b_gc2, R1);
  // 11. window attention -> R2 (o)
  attn_w_k<<<2048, 256, 0, stream>>>(x, w_qkv, RPBT, R2);
  // 12. ox + oy + local -> R3 (out0)
  avgadd_k<<<32768, 256, 0, stream>>>(R2, R1, R3);
  // 13. depthwise 8x8 + bn -> R2
  dw_k<<<dim3(8, 8, 512), 256, 0, stream>>>(R3, w_dw, g_proj, b_proj, R2);
  // 14. 1x1 conv w_pw -> d_out
  pw_k<<<512, 256, 0, stream>>>(R2, w_pw, out);
  (void)in_sizes; (void)n_in; (void)out_size; (void)ws_size;
}